// Round 17
// baseline (385.699 us; speedup 1.0000x reference)
//
#include <hip/hip_runtime.h>
#include <hip/hip_bf16.h>

#define NN 50000
#define NE 600000
#define IN_DIM 128
#define HC 128      // H*C
#define NH 4
#define NC 32
#define NEG_SLOPE 0.2f

#define NTHR 256
#define NTILE 196           // ceil(NN/256) scan tiles; <= 256 CUs -> co-resident
#define WT_TOTAL 86016
#define GLF 391             // ceil(NN/128) gemm blocks (4 waves x 32 rows)
#define GHIST 2344          // ceil(NE/256)

typedef __attribute__((ext_vector_type(8))) short short8;
typedef __attribute__((ext_vector_type(4))) float floatx4;
typedef __attribute__((ext_vector_type(8))) unsigned short ushort8v;

__device__ __forceinline__ float bf2f(unsigned short u) {
    return __uint_as_float(((unsigned)u) << 16);
}
__device__ __forceinline__ unsigned short f2bf(float f) {
    unsigned u = __float_as_uint(f);
    unsigned r = (u + 0x7FFFu + ((u >> 16) & 1u)) >> 16;   // RNE
    return (unsigned short)r;
}

// ============ LDS-free MFMA GEMM wave: 32 rows x OD cols, K=128 ============
// mfma(A=Wt frag, B=x frag) -> D[m=channel][n=node]; packed bf16 stores.
template<typename AT, int OD>
__device__ __forceinline__ void gemm_wave(
    const AT* __restrict__ x, const unsigned short* __restrict__ Wt,
    const float* __restrict__ b, unsigned short* __restrict__ y, int n0, int lane) {
    int quad = lane >> 4, l16 = lane & 15;
    floatx4 acc[2][OD / 16];
    #pragma unroll
    for (int i = 0; i < 2; ++i)
        #pragma unroll
        for (int j = 0; j < OD / 16; ++j) acc[i][j] = (floatx4){0.f, 0.f, 0.f, 0.f};

    int r0 = n0 + l16;      if (r0 >= NN) r0 = NN - 1;
    int r1 = n0 + 16 + l16; if (r1 >= NN) r1 = NN - 1;

    #pragma unroll
    for (int ks = 0; ks < 4; ++ks) {
        int kb = ks * 32 + quad * 8;
        short8 xb0, xb1;
        if constexpr (sizeof(AT) == 4) {
            const float* xr = (const float*)x;
            float4 v0 = *(const float4*)&xr[(size_t)r0 * IN_DIM + kb];
            float4 v1 = *(const float4*)&xr[(size_t)r0 * IN_DIM + kb + 4];
            float4 u0 = *(const float4*)&xr[(size_t)r1 * IN_DIM + kb];
            float4 u1 = *(const float4*)&xr[(size_t)r1 * IN_DIM + kb + 4];
            xb0 = (short8){(short)f2bf(v0.x), (short)f2bf(v0.y), (short)f2bf(v0.z), (short)f2bf(v0.w),
                           (short)f2bf(v1.x), (short)f2bf(v1.y), (short)f2bf(v1.z), (short)f2bf(v1.w)};
            xb1 = (short8){(short)f2bf(u0.x), (short)f2bf(u0.y), (short)f2bf(u0.z), (short)f2bf(u0.w),
                           (short)f2bf(u1.x), (short)f2bf(u1.y), (short)f2bf(u1.z), (short)f2bf(u1.w)};
        } else {
            xb0 = *(const short8*)&((const unsigned short*)x)[(size_t)r0 * IN_DIM + kb];
            xb1 = *(const short8*)&((const unsigned short*)x)[(size_t)r1 * IN_DIM + kb];
        }
        #pragma unroll
        for (int tc = 0; tc < OD / 16; ++tc) {
            short8 af = *(const short8*)&Wt[(size_t)(tc * 16 + l16) * 128 + kb];
            acc[0][tc] = __builtin_amdgcn_mfma_f32_16x16x32_bf16(af, xb0, acc[0][tc], 0, 0, 0);
            acc[1][tc] = __builtin_amdgcn_mfma_f32_16x16x32_bf16(af, xb1, acc[1][tc], 0, 0, 0);
        }
    }

    #pragma unroll
    for (int tc = 0; tc < OD / 16; ++tc) {
        int cbase = tc * 16 + quad * 4;
        float4 bv = *(const float4*)&b[cbase];
        #pragma unroll
        for (int i = 0; i < 2; ++i) {
            int node = n0 + i * 16 + l16;
            if (node < NN) {
                ushort4 pk = {f2bf(acc[i][tc][0] + bv.x), f2bf(acc[i][tc][1] + bv.y),
                              f2bf(acc[i][tc][2] + bv.z), f2bf(acc[i][tc][3] + bv.w)};
                *(ushort4*)&y[(size_t)node * OD + cbase] = pk;
            }
        }
    }
}

// ---------------- per-node GATv2 (1 wave, 4 slots x 16 lanes) ----------------
// Score via leaky(v) = 0.6v + 0.4|v|.
__device__ __forceinline__ void gat_node(
    int n, int lane, const unsigned short* __restrict__ h, const int* __restrict__ rowptr,
    const int* __restrict__ csr_src, const float* __restrict__ att,
    const float* __restrict__ bias, const unsigned short* __restrict__ skip,
    void* __restrict__ out, int last) {
    int slot = lane >> 4;
    int t = lane & 15;

    ushort8v hdv = *(const ushort8v*)(h + (size_t)n * HC + t * 8);
    float hd[8], av[8];
    #pragma unroll
    for (int c = 0; c < 8; ++c) hd[c] = bf2f(hdv[c]);
    float4 av0 = ((const float4*)att)[t * 2];
    float4 av1 = ((const float4*)att)[t * 2 + 1];
    av[0] = av0.x; av[1] = av0.y; av[2] = av0.z; av[3] = av0.w;
    av[4] = av1.x; av[5] = av1.y; av[6] = av1.z; av[7] = av1.w;

    float K = 0.f;
    #pragma unroll
    for (int c = 0; c < 8; ++c) K = fmaf(hd[c], av[c], K);

    int beg = rowptr[n], end = rowptr[n + 1];
    float l = 0.f;
    float acc[8] = {};

    int i0 = beg + slot;
    ushort8v b0 = 0, b1 = 0;
    if (i0 < end)     b0 = *(const ushort8v*)(h + (size_t)csr_src[i0] * HC + t * 8);
    if (i0 + 4 < end) b1 = *(const ushort8v*)(h + (size_t)csr_src[i0 + 4] * HC + t * 8);

    for (int i = i0; i < end; i += 4) {
        float hs[8];
        float S1 = K, S2 = 0.f;
        #pragma unroll
        for (int c = 0; c < 8; ++c) {
            float hsv = bf2f(b0[c]);
            hs[c] = hsv;
            S1 = fmaf(hsv, av[c], S1);
            S2 = fmaf(fabsf(hsv + hd[c]), av[c], S2);
        }
        b0 = b1;
        if (i + 8 < end)
            b1 = *(const ushort8v*)(h + (size_t)csr_src[i + 8] * HC + t * 8);
        float part = fmaf(0.6f, S1, 0.4f * S2);
        part += __shfl_xor(part, 1, 64);
        part += __shfl_xor(part, 2, 64);
        float p = __expf(part);
        #pragma unroll
        for (int c = 0; c < 8; ++c) acc[c] = fmaf(p, hs[c], acc[c]);
        l += p;
    }

    l += __shfl_xor(l, 16, 64);
    l += __shfl_xor(l, 32, 64);
    #pragma unroll
    for (int c = 0; c < 8; ++c) {
        acc[c] += __shfl_xor(acc[c], 16, 64);
        acc[c] += __shfl_xor(acc[c], 32, 64);
    }

    float inv = 1.f / fmaxf(l, 1e-16f);
    float o[8];
    #pragma unroll
    for (int c = 0; c < 8; ++c) o[c] = acc[c] * inv;

    if (!last) {
        if (lane < 16) {
            float4 bv0 = ((const float4*)bias)[t * 2];
            float4 bv1 = ((const float4*)bias)[t * 2 + 1];
            float bb[8] = {bv0.x, bv0.y, bv0.z, bv0.w, bv1.x, bv1.y, bv1.z, bv1.w};
            ushort8v skv = *(const ushort8v*)(skip + (size_t)n * HC + t * 8);
            ushort8v ov;
            #pragma unroll
            for (int c = 0; c < 8; ++c) {
                float r = o[c] + bb[c] + bf2f(skv[c]);
                r = r > 0.f ? r : (__expf(r) - 1.f);   // ELU
                ov[c] = f2bf(r);
            }
            *(ushort8v*)((unsigned short*)out + (size_t)n * HC + t * 8) = ov;
        }
    } else {
        float r4[8], r8[8], r12[8];
        #pragma unroll
        for (int c = 0; c < 8; ++c) {
            r4[c]  = __shfl_down(o[c], 4, 64);
            r8[c]  = __shfl_down(o[c], 8, 64);
            r12[c] = __shfl_down(o[c], 12, 64);
        }
        if (lane < 4) {
            float* op = (float*)out + (size_t)n * NC + lane * 8;
            ushort8v skv = *(const ushort8v*)(skip + (size_t)n * NC + lane * 8);
            float rr[8];
            #pragma unroll
            for (int c = 0; c < 8; ++c) {
                rr[c] = 0.25f * (o[c] + r4[c] + r8[c] + r12[c])
                      + bias[lane * 8 + c] + bf2f(skv[c]);
            }
            *(float4*)op = (float4){rr[0], rr[1], rr[2], rr[3]};
            *(float4*)(op + 4) = (float4){rr[4], rr[5], rr[6], rr[7]};
        }
    }
}

// ---------------- phase kernels ----------------

// transpose weights to bf16 Wt[n][k], zero deg, zero barrier counters
__global__ void k_prep(const float* __restrict__ W0, const float* __restrict__ S0,
                       const float* __restrict__ W1, const float* __restrict__ S1,
                       const float* __restrict__ W2, const float* __restrict__ S2,
                       unsigned short* __restrict__ wt, int* __restrict__ deg,
                       int* __restrict__ bar) {
    int idx = blockIdx.x * blockDim.x + threadIdx.x;
    if (idx < WT_TOTAL) {
        const float* W; int OD; int base;
        int r = idx >> 14;
        if (idx < 81920) {
            OD = 128; base = r << 14;
            W = (r == 0) ? W0 : (r == 1) ? S0 : (r == 2) ? W1 : (r == 3) ? S1 : W2;
        } else { W = S2; OD = 32; base = 81920; }
        int off = idx - base;
        int n = off >> 7, k = off & 127;
        wt[idx] = f2bf(W[(size_t)k * OD + n]);
    } else {
        int i = idx - WT_TOTAL;
        if (i < NN) deg[i] = 0;
        else if (i < NN + 2) bar[i - NN] = 0;
    }
}

// layer-0 dual GEMM + degree histogram, one dispatch (independent work)
__global__ __launch_bounds__(256) void k_gemm0_hist(
    const float* __restrict__ x,
    const unsigned short* __restrict__ Wta, const float* __restrict__ ba, unsigned short* __restrict__ ya,
    const unsigned short* __restrict__ Wtb, const float* __restrict__ bb, unsigned short* __restrict__ yb,
    const int* __restrict__ dst, int* __restrict__ deg) {
    int b = blockIdx.x;
    if (b < 2 * GLF) {
        int wid = threadIdx.x >> 6, lane = threadIdx.x & 63;
        int gb = (b < GLF) ? b : b - GLF;
        int n0 = (gb * 4 + wid) * 32;
        if (n0 >= NN) return;
        if (b < GLF) gemm_wave<float, 128>(x, Wta, ba, ya, n0, lane);
        else         gemm_wave<float, 128>(x, Wtb, bb, yb, n0, lane);
    } else {
        int e = (b - 2 * GLF) * 256 + threadIdx.x;
        if (e < NE) atomicAdd(&deg[dst[e]], 1);
    }
}

// merged scan + apply + scatter: NTILE(196) blocks <= 256 CUs -> co-resident,
// inter-block barriers via device-scope atomic counters are deadlock-free.
__global__ __launch_bounds__(NTHR) void k_csr(
    const int* __restrict__ deg, int* __restrict__ blocksum,
    int* __restrict__ rowptr, int* __restrict__ cursor,
    const int* __restrict__ src, const int* __restrict__ dst,
    int* __restrict__ csr_src, int* __restrict__ bar) {
    __shared__ int sh[NTHR];
    int b = blockIdx.x, t = threadIdx.x;

    // phase A: per-tile inclusive scan, keep tile in LDS, publish tile sum
    int i = b * NTHR + t;
    int d = (i < NN) ? deg[i] : 0;
    sh[t] = d;
    __syncthreads();
    #pragma unroll
    for (int off = 1; off < NTHR; off <<= 1) {
        int v = (t >= off) ? sh[t - off] : 0;
        __syncthreads();
        sh[t] += v;
        __syncthreads();
    }
    int my_inc = sh[t];            // inclusive within tile
    if (t == NTHR - 1) blocksum[b] = sh[t];
    __threadfence();
    __syncthreads();
    if (t == 0) {
        __hip_atomic_fetch_add(&bar[0], 1, __ATOMIC_RELEASE, __HIP_MEMORY_SCOPE_AGENT);
        while (__hip_atomic_load(&bar[0], __ATOMIC_ACQUIRE, __HIP_MEMORY_SCOPE_AGENT) < NTILE) {}
    }
    __syncthreads();

    // phase B: every block scans all tile sums, applies its tile offset
    int v = (t < NTILE) ? blocksum[t] : 0;
    sh[t] = v;
    __syncthreads();
    #pragma unroll
    for (int off = 1; off < NTHR; off <<= 1) {
        int u = (t >= off) ? sh[t - off] : 0;
        __syncthreads();
        sh[t] += u;
        __syncthreads();
    }
    int tile_off = (b > 0) ? sh[b - 1] : 0;
    if (i < NN) {
        int inc = my_inc + tile_off;
        rowptr[i + 1] = inc;
        cursor[i] = inc - d;
        if (i == 0) rowptr[0] = 0;
    }
    __threadfence();
    __syncthreads();
    if (t == 0) {
        __hip_atomic_fetch_add(&bar[1], 1, __ATOMIC_RELEASE, __HIP_MEMORY_SCOPE_AGENT);
        while (__hip_atomic_load(&bar[1], __ATOMIC_ACQUIRE, __HIP_MEMORY_SCOPE_AGENT) < NTILE) {}
    }
    __syncthreads();

    // phase C: grid-stride scatter
    for (int e = b * NTHR + t; e < NE; e += NTILE * NTHR) {
        int dd = dst[e];
        int pos = atomicAdd(&cursor[dd], 1);
        csr_src[pos] = src[e];
    }
}

template<typename AT>
__global__ __launch_bounds__(256) void k_gemm_dual_lf(
    const AT* __restrict__ x,
    const unsigned short* __restrict__ Wta, const float* __restrict__ ba, unsigned short* __restrict__ ya,
    const unsigned short* __restrict__ Wtb, const float* __restrict__ bb, unsigned short* __restrict__ yb) {
    int wid = threadIdx.x >> 6, lane = threadIdx.x & 63;
    int n0 = (blockIdx.x * 4 + wid) * 32;
    if (n0 >= NN) return;
    if (blockIdx.y == 0) gemm_wave<AT, 128>(x, Wta, ba, ya, n0, lane);
    else                 gemm_wave<AT, 128>(x, Wtb, bb, yb, n0, lane);
}

__global__ __launch_bounds__(256) void k_gemm_dual_l2(
    const unsigned short* __restrict__ x,
    const unsigned short* __restrict__ Wta, const float* __restrict__ ba, unsigned short* __restrict__ ya,
    const unsigned short* __restrict__ Wtb, const float* __restrict__ bb, unsigned short* __restrict__ yb) {
    int wid = threadIdx.x >> 6, lane = threadIdx.x & 63;
    int n0 = (blockIdx.x * 4 + wid) * 32;
    if (n0 >= NN) return;
    if (blockIdx.y == 0) gemm_wave<unsigned short, 128>(x, Wta, ba, ya, n0, lane);
    else                 gemm_wave<unsigned short, 32>(x, Wtb, bb, yb, n0, lane);
}

__global__ __launch_bounds__(256) void k_gat(
    const unsigned short* __restrict__ h, const int* __restrict__ rowptr,
    const int* __restrict__ csr_src, const float* __restrict__ att,
    const float* __restrict__ bias, const unsigned short* __restrict__ skip,
    void* __restrict__ out, int last) {
    int wid = threadIdx.x >> 6;
    int n = blockIdx.x * 4 + wid;
    if (n >= NN) return;
    gat_node(n, threadIdx.x & 63, h, rowptr, csr_src, att, bias, skip, out, last);
}

extern "C" void kernel_launch(void* const* d_in, const int* in_sizes, int n_in,
                              void* d_out, int out_size, void* d_ws, size_t ws_size,
                              hipStream_t stream) {
    const float* x0 = (const float*)d_in[0];
    const int* ei = (const int*)d_in[1];
    const int* src = ei;
    const int* dst = ei + NE;

    unsigned short* xbuf = (unsigned short*)d_ws;            // NN*HC bf16
    unsigned short* h    = xbuf + (size_t)NN * HC;           // NN*HC bf16
    unsigned short* skip = h + (size_t)NN * HC;              // NN*HC bf16
    int* deg     = (int*)(skip + (size_t)NN * HC);           // NN
    int* rowptr  = deg + NN;                                 // NN+1
    int* cursor  = rowptr + NN + 1;                          // NN
    int* blocksum = cursor + NN;                             // NTILE
    int* bar     = blocksum + NTILE;                         // 2
    uintptr_t pa = (uintptr_t)(bar + 2);
    pa = (pa + 15) & ~(uintptr_t)15;
    unsigned short* wt = (unsigned short*)pa;                // WT_TOTAL bf16
    int* csr_src = (int*)(wt + WT_TOTAL);                    // NE

    unsigned short* wtW[3] = {wt, wt + 32768, wt + 65536};
    unsigned short* wtS[3] = {wt + 16384, wt + 49152, wt + 81920};

    const float* linb0  = (const float*)d_in[3];
    const float* skipb0 = (const float*)d_in[7];

    // 1) prep: transpose weights, zero deg + barriers
    k_prep<<<(WT_TOTAL + NN + 2 + 255) / 256, 256, 0, stream>>>(
        (const float*)d_in[2], (const float*)d_in[6],
        (const float*)d_in[8], (const float*)d_in[12],
        (const float*)d_in[14], (const float*)d_in[18], wt, deg, bar);

    // 2) layer-0 dual GEMM + histogram (independent, one dispatch)
    k_gemm0_hist<<<2 * GLF + GHIST, 256, 0, stream>>>(
        x0, wtW[0], linb0, h, wtS[0], skipb0, skip, dst, deg);

    // 3) merged scan + apply + scatter (co-resident barrier kernel)
    k_csr<<<NTILE, NTHR, 0, stream>>>(deg, blocksum, rowptr, cursor, src, dst, csr_src, bar);

    const int GGAT = (NN + 3) / 4;

    for (int l = 0; l < 3; ++l) {
        const float* linb  = (const float*)d_in[2 + 6 * l + 1];
        const float* att   = (const float*)d_in[2 + 6 * l + 2];
        const float* bias  = (const float*)d_in[2 + 6 * l + 3];
        const float* skipb = (const float*)d_in[2 + 6 * l + 5];

        if (l == 1) {
            k_gemm_dual_lf<unsigned short><<<dim3(GLF, 2), 256, 0, stream>>>(
                xbuf, wtW[1], linb, h, wtS[1], skipb, skip);
        } else if (l == 2) {
            k_gemm_dual_l2<<<dim3(GLF, 2), 256, 0, stream>>>(
                xbuf, wtW[2], linb, h, wtS[2], skipb, skip);
        }
        void* outp = (l < 2) ? (void*)xbuf : (void*)d_out;
        k_gat<<<GGAT, 256, 0, stream>>>(h, rowptr, csr_src, att, bias, skip, outp, l == 2);
    }
}

// Round 18
// 347.837 us; speedup vs baseline: 1.1089x; 1.1089x over previous
//
#include <hip/hip_runtime.h>
#include <hip/hip_bf16.h>

#define NN 50000
#define NE 600000
#define IN_DIM 128
#define HC 128      // H*C
#define NH 4
#define NC 32
#define NEG_SLOPE 0.2f

#define NTHR 256
#define NTILE 196           // ceil(NN/256) scan tiles
#define WT_TOTAL 86016
#define GLF 391             // ceil(NN/128) gemm blocks (4 waves x 32 rows)
#define GHIST 2344          // ceil(NE/256)

typedef __attribute__((ext_vector_type(8))) short short8;
typedef __attribute__((ext_vector_type(4))) float floatx4;
typedef __attribute__((ext_vector_type(8))) unsigned short ushort8v;

__device__ __forceinline__ float bf2f(unsigned short u) {
    return __uint_as_float(((unsigned)u) << 16);
}
__device__ __forceinline__ unsigned short f2bf(float f) {
    unsigned u = __float_as_uint(f);
    unsigned r = (u + 0x7FFFu + ((u >> 16) & 1u)) >> 16;   // RNE
    return (unsigned short)r;
}

// ============ LDS-free MFMA GEMM wave: 32 rows x OD cols, K=128 ============
// mfma(A=Wt frag, B=x frag) -> D[m=channel][n=node]; packed bf16 stores.
template<typename AT, int OD>
__device__ __forceinline__ void gemm_wave(
    const AT* __restrict__ x, const unsigned short* __restrict__ Wt,
    const float* __restrict__ b, unsigned short* __restrict__ y, int n0, int lane) {
    int quad = lane >> 4, l16 = lane & 15;
    floatx4 acc[2][OD / 16];
    #pragma unroll
    for (int i = 0; i < 2; ++i)
        #pragma unroll
        for (int j = 0; j < OD / 16; ++j) acc[i][j] = (floatx4){0.f, 0.f, 0.f, 0.f};

    int r0 = n0 + l16;      if (r0 >= NN) r0 = NN - 1;
    int r1 = n0 + 16 + l16; if (r1 >= NN) r1 = NN - 1;

    #pragma unroll
    for (int ks = 0; ks < 4; ++ks) {
        int kb = ks * 32 + quad * 8;
        short8 xb0, xb1;
        if constexpr (sizeof(AT) == 4) {
            const float* xr = (const float*)x;
            float4 v0 = *(const float4*)&xr[(size_t)r0 * IN_DIM + kb];
            float4 v1 = *(const float4*)&xr[(size_t)r0 * IN_DIM + kb + 4];
            float4 u0 = *(const float4*)&xr[(size_t)r1 * IN_DIM + kb];
            float4 u1 = *(const float4*)&xr[(size_t)r1 * IN_DIM + kb + 4];
            xb0 = (short8){(short)f2bf(v0.x), (short)f2bf(v0.y), (short)f2bf(v0.z), (short)f2bf(v0.w),
                           (short)f2bf(v1.x), (short)f2bf(v1.y), (short)f2bf(v1.z), (short)f2bf(v1.w)};
            xb1 = (short8){(short)f2bf(u0.x), (short)f2bf(u0.y), (short)f2bf(u0.z), (short)f2bf(u0.w),
                           (short)f2bf(u1.x), (short)f2bf(u1.y), (short)f2bf(u1.z), (short)f2bf(u1.w)};
        } else {
            xb0 = *(const short8*)&((const unsigned short*)x)[(size_t)r0 * IN_DIM + kb];
            xb1 = *(const short8*)&((const unsigned short*)x)[(size_t)r1 * IN_DIM + kb];
        }
        #pragma unroll
        for (int tc = 0; tc < OD / 16; ++tc) {
            short8 af = *(const short8*)&Wt[(size_t)(tc * 16 + l16) * 128 + kb];
            acc[0][tc] = __builtin_amdgcn_mfma_f32_16x16x32_bf16(af, xb0, acc[0][tc], 0, 0, 0);
            acc[1][tc] = __builtin_amdgcn_mfma_f32_16x16x32_bf16(af, xb1, acc[1][tc], 0, 0, 0);
        }
    }

    #pragma unroll
    for (int tc = 0; tc < OD / 16; ++tc) {
        int cbase = tc * 16 + quad * 4;
        float4 bv = *(const float4*)&b[cbase];
        #pragma unroll
        for (int i = 0; i < 2; ++i) {
            int node = n0 + i * 16 + l16;
            if (node < NN) {
                ushort4 pk = {f2bf(acc[i][tc][0] + bv.x), f2bf(acc[i][tc][1] + bv.y),
                              f2bf(acc[i][tc][2] + bv.z), f2bf(acc[i][tc][3] + bv.w)};
                *(ushort4*)&y[(size_t)node * OD + cbase] = pk;
            }
        }
    }
}

// ---------------- per-node GATv2 (1 wave, 4 slots x 16 lanes) ----------------
// Score via leaky(v) = 0.6v + 0.4|v|.
__device__ __forceinline__ void gat_node(
    int n, int lane, const unsigned short* __restrict__ h, const int* __restrict__ rowptr,
    const int* __restrict__ csr_src, const float* __restrict__ att,
    const float* __restrict__ bias, const unsigned short* __restrict__ skip,
    void* __restrict__ out, int last) {
    int slot = lane >> 4;
    int t = lane & 15;

    ushort8v hdv = *(const ushort8v*)(h + (size_t)n * HC + t * 8);
    float hd[8], av[8];
    #pragma unroll
    for (int c = 0; c < 8; ++c) hd[c] = bf2f(hdv[c]);
    float4 av0 = ((const float4*)att)[t * 2];
    float4 av1 = ((const float4*)att)[t * 2 + 1];
    av[0] = av0.x; av[1] = av0.y; av[2] = av0.z; av[3] = av0.w;
    av[4] = av1.x; av[5] = av1.y; av[6] = av1.z; av[7] = av1.w;

    float K = 0.f;
    #pragma unroll
    for (int c = 0; c < 8; ++c) K = fmaf(hd[c], av[c], K);

    int beg = rowptr[n], end = rowptr[n + 1];
    float l = 0.f;
    float acc[8] = {};

    int i0 = beg + slot;
    ushort8v b0 = 0, b1 = 0;
    if (i0 < end)     b0 = *(const ushort8v*)(h + (size_t)csr_src[i0] * HC + t * 8);
    if (i0 + 4 < end) b1 = *(const ushort8v*)(h + (size_t)csr_src[i0 + 4] * HC + t * 8);

    for (int i = i0; i < end; i += 4) {
        float hs[8];
        float S1 = K, S2 = 0.f;
        #pragma unroll
        for (int c = 0; c < 8; ++c) {
            float hsv = bf2f(b0[c]);
            hs[c] = hsv;
            S1 = fmaf(hsv, av[c], S1);
            S2 = fmaf(fabsf(hsv + hd[c]), av[c], S2);
        }
        b0 = b1;
        if (i + 8 < end)
            b1 = *(const ushort8v*)(h + (size_t)csr_src[i + 8] * HC + t * 8);
        float part = fmaf(0.6f, S1, 0.4f * S2);
        part += __shfl_xor(part, 1, 64);
        part += __shfl_xor(part, 2, 64);
        float p = __expf(part);
        #pragma unroll
        for (int c = 0; c < 8; ++c) acc[c] = fmaf(p, hs[c], acc[c]);
        l += p;
    }

    l += __shfl_xor(l, 16, 64);
    l += __shfl_xor(l, 32, 64);
    #pragma unroll
    for (int c = 0; c < 8; ++c) {
        acc[c] += __shfl_xor(acc[c], 16, 64);
        acc[c] += __shfl_xor(acc[c], 32, 64);
    }

    float inv = 1.f / fmaxf(l, 1e-16f);
    float o[8];
    #pragma unroll
    for (int c = 0; c < 8; ++c) o[c] = acc[c] * inv;

    if (!last) {
        if (lane < 16) {
            float4 bv0 = ((const float4*)bias)[t * 2];
            float4 bv1 = ((const float4*)bias)[t * 2 + 1];
            float bb[8] = {bv0.x, bv0.y, bv0.z, bv0.w, bv1.x, bv1.y, bv1.z, bv1.w};
            ushort8v skv = *(const ushort8v*)(skip + (size_t)n * HC + t * 8);
            ushort8v ov;
            #pragma unroll
            for (int c = 0; c < 8; ++c) {
                float r = o[c] + bb[c] + bf2f(skv[c]);
                r = r > 0.f ? r : (__expf(r) - 1.f);   // ELU
                ov[c] = f2bf(r);
            }
            *(ushort8v*)((unsigned short*)out + (size_t)n * HC + t * 8) = ov;
        }
    } else {
        float r4[8], r8[8], r12[8];
        #pragma unroll
        for (int c = 0; c < 8; ++c) {
            r4[c]  = __shfl_down(o[c], 4, 64);
            r8[c]  = __shfl_down(o[c], 8, 64);
            r12[c] = __shfl_down(o[c], 12, 64);
        }
        if (lane < 4) {
            float* op = (float*)out + (size_t)n * NC + lane * 8;
            ushort8v skv = *(const ushort8v*)(skip + (size_t)n * NC + lane * 8);
            float rr[8];
            #pragma unroll
            for (int c = 0; c < 8; ++c) {
                rr[c] = 0.25f * (o[c] + r4[c] + r8[c] + r12[c])
                      + bias[lane * 8 + c] + bf2f(skv[c]);
            }
            *(float4*)op = (float4){rr[0], rr[1], rr[2], rr[3]};
            *(float4*)(op + 4) = (float4){rr[4], rr[5], rr[6], rr[7]};
        }
    }
}

// ---------------- phase kernels ----------------

// transpose weights to bf16 Wt[n][k] AND zero deg (extra blocks)
__global__ void k_prep(const float* __restrict__ W0, const float* __restrict__ S0,
                       const float* __restrict__ W1, const float* __restrict__ S1,
                       const float* __restrict__ W2, const float* __restrict__ S2,
                       unsigned short* __restrict__ wt, int* __restrict__ deg) {
    int idx = blockIdx.x * blockDim.x + threadIdx.x;
    if (idx < WT_TOTAL) {
        const float* W; int OD; int base;
        int r = idx >> 14;
        if (idx < 81920) {
            OD = 128; base = r << 14;
            W = (r == 0) ? W0 : (r == 1) ? S0 : (r == 2) ? W1 : (r == 3) ? S1 : W2;
        } else { W = S2; OD = 32; base = 81920; }
        int off = idx - base;
        int n = off >> 7, k = off & 127;
        wt[idx] = f2bf(W[(size_t)k * OD + n]);
    } else {
        int i = idx - WT_TOTAL;
        if (i < NN) deg[i] = 0;
    }
}

// layer-0 dual GEMM + degree histogram, one dispatch (independent work)
__global__ __launch_bounds__(256) void k_gemm0_hist(
    const float* __restrict__ x,
    const unsigned short* __restrict__ Wta, const float* __restrict__ ba, unsigned short* __restrict__ ya,
    const unsigned short* __restrict__ Wtb, const float* __restrict__ bb, unsigned short* __restrict__ yb,
    const int* __restrict__ dst, int* __restrict__ deg) {
    int b = blockIdx.x;
    if (b < 2 * GLF) {
        int wid = threadIdx.x >> 6, lane = threadIdx.x & 63;
        int gb = (b < GLF) ? b : b - GLF;
        int n0 = (gb * 4 + wid) * 32;
        if (n0 >= NN) return;
        if (b < GLF) gemm_wave<float, 128>(x, Wta, ba, ya, n0, lane);
        else         gemm_wave<float, 128>(x, Wtb, bb, yb, n0, lane);
    } else {
        int e = (b - 2 * GLF) * 256 + threadIdx.x;
        if (e < NE) atomicAdd(&deg[dst[e]], 1);
    }
}

__global__ __launch_bounds__(NTHR) void k_scan1(const int* __restrict__ deg,
                                                int* __restrict__ partial,
                                                int* __restrict__ blocksum) {
    __shared__ int sh[NTHR];
    int b = blockIdx.x, t = threadIdx.x;
    int i = b * NTHR + t;
    int d = (i < NN) ? deg[i] : 0;
    sh[t] = d;
    __syncthreads();
    #pragma unroll
    for (int off = 1; off < NTHR; off <<= 1) {
        int v = (t >= off) ? sh[t - off] : 0;
        __syncthreads();
        sh[t] += v;
        __syncthreads();
    }
    if (i < NN) partial[i] = sh[t];
    if (t == NTHR - 1) blocksum[b] = sh[t];
}

// merged scan2+scan3: each block redundantly scans 196 tile sums in-LDS,
// then applies its tile's exclusive offset -> rowptr, cursor.
__global__ __launch_bounds__(NTHR) void k_scan23(const int* __restrict__ deg,
                                                 const int* __restrict__ partial,
                                                 const int* __restrict__ blocksum,
                                                 int* __restrict__ rowptr,
                                                 int* __restrict__ cursor) {
    __shared__ int sh[NTHR];
    int b = blockIdx.x, t = threadIdx.x;
    int v = (t < NTILE) ? blocksum[t] : 0;
    sh[t] = v;
    __syncthreads();
    #pragma unroll
    for (int off = 1; off < NTHR; off <<= 1) {
        int u = (t >= off) ? sh[t - off] : 0;
        __syncthreads();
        sh[t] += u;
        __syncthreads();
    }
    int tile_off = (b > 0) ? sh[b - 1] : 0;
    int i = b * NTHR + t;
    if (i < NN) {
        int inc = partial[i] + tile_off;
        rowptr[i + 1] = inc;
        cursor[i] = inc - deg[i];
        if (i == 0) rowptr[0] = 0;
    }
}

__global__ void k_scatter(const int* __restrict__ src, const int* __restrict__ dst,
                          int* __restrict__ cursor, int* __restrict__ csr_src) {
    int e = blockIdx.x * blockDim.x + threadIdx.x;
    if (e >= NE) return;
    int d = dst[e];
    int pos = atomicAdd(&cursor[d], 1);
    csr_src[pos] = src[e];
}

template<typename AT>
__global__ __launch_bounds__(256) void k_gemm_dual_lf(
    const AT* __restrict__ x,
    const unsigned short* __restrict__ Wta, const float* __restrict__ ba, unsigned short* __restrict__ ya,
    const unsigned short* __restrict__ Wtb, const float* __restrict__ bb, unsigned short* __restrict__ yb) {
    int wid = threadIdx.x >> 6, lane = threadIdx.x & 63;
    int n0 = (blockIdx.x * 4 + wid) * 32;
    if (n0 >= NN) return;
    if (blockIdx.y == 0) gemm_wave<AT, 128>(x, Wta, ba, ya, n0, lane);
    else                 gemm_wave<AT, 128>(x, Wtb, bb, yb, n0, lane);
}

__global__ __launch_bounds__(256) void k_gemm_dual_l2(
    const unsigned short* __restrict__ x,
    const unsigned short* __restrict__ Wta, const float* __restrict__ ba, unsigned short* __restrict__ ya,
    const unsigned short* __restrict__ Wtb, const float* __restrict__ bb, unsigned short* __restrict__ yb) {
    int wid = threadIdx.x >> 6, lane = threadIdx.x & 63;
    int n0 = (blockIdx.x * 4 + wid) * 32;
    if (n0 >= NN) return;
    if (blockIdx.y == 0) gemm_wave<unsigned short, 128>(x, Wta, ba, ya, n0, lane);
    else                 gemm_wave<unsigned short, 32>(x, Wtb, bb, yb, n0, lane);
}

__global__ __launch_bounds__(256) void k_gat(
    const unsigned short* __restrict__ h, const int* __restrict__ rowptr,
    const int* __restrict__ csr_src, const float* __restrict__ att,
    const float* __restrict__ bias, const unsigned short* __restrict__ skip,
    void* __restrict__ out, int last) {
    int wid = threadIdx.x >> 6;
    int n = blockIdx.x * 4 + wid;
    if (n >= NN) return;
    gat_node(n, threadIdx.x & 63, h, rowptr, csr_src, att, bias, skip, out, last);
}

extern "C" void kernel_launch(void* const* d_in, const int* in_sizes, int n_in,
                              void* d_out, int out_size, void* d_ws, size_t ws_size,
                              hipStream_t stream) {
    const float* x0 = (const float*)d_in[0];
    const int* ei = (const int*)d_in[1];
    const int* src = ei;
    const int* dst = ei + NE;

    unsigned short* xbuf = (unsigned short*)d_ws;            // NN*HC bf16
    unsigned short* h    = xbuf + (size_t)NN * HC;           // NN*HC bf16
    unsigned short* skip = h + (size_t)NN * HC;              // NN*HC bf16
    int* deg     = (int*)(skip + (size_t)NN * HC);           // NN
    int* rowptr  = deg + NN;                                 // NN+1
    int* cursor  = rowptr + NN + 1;                          // NN
    int* partial = cursor + NN;                              // NN
    int* blocksum = partial + NN;                            // NTILE
    uintptr_t pa = (uintptr_t)(blocksum + NTILE);
    pa = (pa + 15) & ~(uintptr_t)15;
    unsigned short* wt = (unsigned short*)pa;                // WT_TOTAL bf16
    int* csr_src = (int*)(wt + WT_TOTAL);                    // NE

    unsigned short* wtW[3] = {wt, wt + 32768, wt + 65536};
    unsigned short* wtS[3] = {wt + 16384, wt + 49152, wt + 81920};

    const float* linb0  = (const float*)d_in[3];
    const float* skipb0 = (const float*)d_in[7];

    // 1) prep: transpose weights, zero deg
    k_prep<<<(WT_TOTAL + NN + 255) / 256, 256, 0, stream>>>(
        (const float*)d_in[2], (const float*)d_in[6],
        (const float*)d_in[8], (const float*)d_in[12],
        (const float*)d_in[14], (const float*)d_in[18], wt, deg);

    // 2) layer-0 dual GEMM + histogram (independent, one dispatch)
    k_gemm0_hist<<<2 * GLF + GHIST, 256, 0, stream>>>(
        x0, wtW[0], linb0, h, wtS[0], skipb0, skip, dst, deg);

    // 3-5) CSR: scan, apply, scatter (full-width kernels)
    k_scan1<<<NTILE, NTHR, 0, stream>>>(deg, partial, blocksum);
    k_scan23<<<NTILE, NTHR, 0, stream>>>(deg, partial, blocksum, rowptr, cursor);
    k_scatter<<<GHIST, 256, 0, stream>>>(src, dst, cursor, csr_src);

    const int GGAT = (NN + 3) / 4;

    for (int l = 0; l < 3; ++l) {
        const float* linb  = (const float*)d_in[2 + 6 * l + 1];
        const float* att   = (const float*)d_in[2 + 6 * l + 2];
        const float* bias  = (const float*)d_in[2 + 6 * l + 3];
        const float* skipb = (const float*)d_in[2 + 6 * l + 5];

        if (l == 1) {
            k_gemm_dual_lf<unsigned short><<<dim3(GLF, 2), 256, 0, stream>>>(
                xbuf, wtW[1], linb, h, wtS[1], skipb, skip);
        } else if (l == 2) {
            k_gemm_dual_l2<<<dim3(GLF, 2), 256, 0, stream>>>(
                xbuf, wtW[2], linb, h, wtS[2], skipb, skip);
        }
        void* outp = (l < 2) ? (void*)xbuf : (void*)d_out;
        k_gat<<<GGAT, 256, 0, stream>>>(h, rowptr, csr_src, att, bias, skip, outp, l == 2);
    }
}

// Round 19
// 347.006 us; speedup vs baseline: 1.1115x; 1.0024x over previous
//
#include <hip/hip_runtime.h>
#include <hip/hip_bf16.h>

#define NN 50000
#define NE 600000
#define IN_DIM 128
#define HC 128      // H*C
#define NH 4
#define NC 32
#define NEG_SLOPE 0.2f

#define NTHR 256
#define NTILE 196           // ceil(NN/256) scan tiles
#define WT_TOTAL 86016
#define GLF 391             // ceil(NN/128): 4 waves x 32 rows per block
#define GHIST 2344          // ceil(NE/256)

typedef __attribute__((ext_vector_type(8))) short short8;
typedef __attribute__((ext_vector_type(4))) float floatx4;
typedef __attribute__((ext_vector_type(8))) unsigned short ushort8v;

__device__ __forceinline__ float bf2f(unsigned short u) {
    return __uint_as_float(((unsigned)u) << 16);
}
__device__ __forceinline__ unsigned short f2bf(float f) {
    unsigned u = __float_as_uint(f);
    unsigned r = (u + 0x7FFFu + ((u >> 16) & 1u)) >> 16;   // RNE
    return (unsigned short)r;
}

// ============ LDS-free MFMA GEMM wave: 32 rows x (NTC*16) cols, K=128 ============
// mfma(A=Wt frag, B=x frag) -> D[m=channel][n=node]; packed bf16 stores.
// c0 = column base within OD; halved column range doubles wave-parallelism.
template<typename AT, int OD, int NTC>
__device__ __forceinline__ void gemm_wave(
    const AT* __restrict__ x, const unsigned short* __restrict__ Wt,
    const float* __restrict__ b, unsigned short* __restrict__ y,
    int n0, int c0, int lane) {
    int quad = lane >> 4, l16 = lane & 15;
    floatx4 acc[2][NTC];
    #pragma unroll
    for (int i = 0; i < 2; ++i)
        #pragma unroll
        for (int j = 0; j < NTC; ++j) acc[i][j] = (floatx4){0.f, 0.f, 0.f, 0.f};

    int r0 = n0 + l16;      if (r0 >= NN) r0 = NN - 1;
    int r1 = n0 + 16 + l16; if (r1 >= NN) r1 = NN - 1;

    #pragma unroll
    for (int ks = 0; ks < 4; ++ks) {
        int kb = ks * 32 + quad * 8;
        short8 xb0, xb1;
        if constexpr (sizeof(AT) == 4) {
            const float* xr = (const float*)x;
            float4 v0 = *(const float4*)&xr[(size_t)r0 * IN_DIM + kb];
            float4 v1 = *(const float4*)&xr[(size_t)r0 * IN_DIM + kb + 4];
            float4 u0 = *(const float4*)&xr[(size_t)r1 * IN_DIM + kb];
            float4 u1 = *(const float4*)&xr[(size_t)r1 * IN_DIM + kb + 4];
            xb0 = (short8){(short)f2bf(v0.x), (short)f2bf(v0.y), (short)f2bf(v0.z), (short)f2bf(v0.w),
                           (short)f2bf(v1.x), (short)f2bf(v1.y), (short)f2bf(v1.z), (short)f2bf(v1.w)};
            xb1 = (short8){(short)f2bf(u0.x), (short)f2bf(u0.y), (short)f2bf(u0.z), (short)f2bf(u0.w),
                           (short)f2bf(u1.x), (short)f2bf(u1.y), (short)f2bf(u1.z), (short)f2bf(u1.w)};
        } else {
            xb0 = *(const short8*)&((const unsigned short*)x)[(size_t)r0 * IN_DIM + kb];
            xb1 = *(const short8*)&((const unsigned short*)x)[(size_t)r1 * IN_DIM + kb];
        }
        #pragma unroll
        for (int tc = 0; tc < NTC; ++tc) {
            short8 af = *(const short8*)&Wt[(size_t)(c0 + tc * 16 + l16) * 128 + kb];
            acc[0][tc] = __builtin_amdgcn_mfma_f32_16x16x32_bf16(af, xb0, acc[0][tc], 0, 0, 0);
            acc[1][tc] = __builtin_amdgcn_mfma_f32_16x16x32_bf16(af, xb1, acc[1][tc], 0, 0, 0);
        }
    }

    #pragma unroll
    for (int tc = 0; tc < NTC; ++tc) {
        int cbase = c0 + tc * 16 + quad * 4;
        float4 bv = *(const float4*)&b[cbase];
        #pragma unroll
        for (int i = 0; i < 2; ++i) {
            int node = n0 + i * 16 + l16;
            if (node < NN) {
                ushort4 pk = {f2bf(acc[i][tc][0] + bv.x), f2bf(acc[i][tc][1] + bv.y),
                              f2bf(acc[i][tc][2] + bv.z), f2bf(acc[i][tc][3] + bv.w)};
                *(ushort4*)&y[(size_t)node * OD + cbase] = pk;
            }
        }
    }
}

// ---------------- per-node GATv2 (1 wave, 4 slots x 16 lanes) ----------------
// Score via leaky(v) = 0.6v + 0.4|v|.
__device__ __forceinline__ void gat_node(
    int n, int lane, const unsigned short* __restrict__ h, const int* __restrict__ rowptr,
    const int* __restrict__ csr_src, const float* __restrict__ att,
    const float* __restrict__ bias, const unsigned short* __restrict__ skip,
    void* __restrict__ out, int last) {
    int slot = lane >> 4;
    int t = lane & 15;

    ushort8v hdv = *(const ushort8v*)(h + (size_t)n * HC + t * 8);
    float hd[8], av[8];
    #pragma unroll
    for (int c = 0; c < 8; ++c) hd[c] = bf2f(hdv[c]);
    float4 av0 = ((const float4*)att)[t * 2];
    float4 av1 = ((const float4*)att)[t * 2 + 1];
    av[0] = av0.x; av[1] = av0.y; av[2] = av0.z; av[3] = av0.w;
    av[4] = av1.x; av[5] = av1.y; av[6] = av1.z; av[7] = av1.w;

    float K = 0.f;
    #pragma unroll
    for (int c = 0; c < 8; ++c) K = fmaf(hd[c], av[c], K);

    int beg = rowptr[n], end = rowptr[n + 1];
    float l = 0.f;
    float acc[8] = {};

    int i0 = beg + slot;
    ushort8v b0 = 0, b1 = 0;
    if (i0 < end)     b0 = *(const ushort8v*)(h + (size_t)csr_src[i0] * HC + t * 8);
    if (i0 + 4 < end) b1 = *(const ushort8v*)(h + (size_t)csr_src[i0 + 4] * HC + t * 8);

    for (int i = i0; i < end; i += 4) {
        float hs[8];
        float S1 = K, S2 = 0.f;
        #pragma unroll
        for (int c = 0; c < 8; ++c) {
            float hsv = bf2f(b0[c]);
            hs[c] = hsv;
            S1 = fmaf(hsv, av[c], S1);
            S2 = fmaf(fabsf(hsv + hd[c]), av[c], S2);
        }
        b0 = b1;
        if (i + 8 < end)
            b1 = *(const ushort8v*)(h + (size_t)csr_src[i + 8] * HC + t * 8);
        float part = fmaf(0.6f, S1, 0.4f * S2);
        part += __shfl_xor(part, 1, 64);
        part += __shfl_xor(part, 2, 64);
        float p = __expf(part);
        #pragma unroll
        for (int c = 0; c < 8; ++c) acc[c] = fmaf(p, hs[c], acc[c]);
        l += p;
    }

    l += __shfl_xor(l, 16, 64);
    l += __shfl_xor(l, 32, 64);
    #pragma unroll
    for (int c = 0; c < 8; ++c) {
        acc[c] += __shfl_xor(acc[c], 16, 64);
        acc[c] += __shfl_xor(acc[c], 32, 64);
    }

    float inv = 1.f / fmaxf(l, 1e-16f);
    float o[8];
    #pragma unroll
    for (int c = 0; c < 8; ++c) o[c] = acc[c] * inv;

    if (!last) {
        if (lane < 16) {
            float4 bv0 = ((const float4*)bias)[t * 2];
            float4 bv1 = ((const float4*)bias)[t * 2 + 1];
            float bb[8] = {bv0.x, bv0.y, bv0.z, bv0.w, bv1.x, bv1.y, bv1.z, bv1.w};
            ushort8v skv = *(const ushort8v*)(skip + (size_t)n * HC + t * 8);
            ushort8v ov;
            #pragma unroll
            for (int c = 0; c < 8; ++c) {
                float r = o[c] + bb[c] + bf2f(skv[c]);
                r = r > 0.f ? r : (__expf(r) - 1.f);   // ELU
                ov[c] = f2bf(r);
            }
            *(ushort8v*)((unsigned short*)out + (size_t)n * HC + t * 8) = ov;
        }
    } else {
        float r4[8], r8[8], r12[8];
        #pragma unroll
        for (int c = 0; c < 8; ++c) {
            r4[c]  = __shfl_down(o[c], 4, 64);
            r8[c]  = __shfl_down(o[c], 8, 64);
            r12[c] = __shfl_down(o[c], 12, 64);
        }
        if (lane < 4) {
            float* op = (float*)out + (size_t)n * NC + lane * 8;
            ushort8v skv = *(const ushort8v*)(skip + (size_t)n * NC + lane * 8);
            float rr[8];
            #pragma unroll
            for (int c = 0; c < 8; ++c) {
                rr[c] = 0.25f * (o[c] + r4[c] + r8[c] + r12[c])
                      + bias[lane * 8 + c] + bf2f(skv[c]);
            }
            *(float4*)op = (float4){rr[0], rr[1], rr[2], rr[3]};
            *(float4*)(op + 4) = (float4){rr[4], rr[5], rr[6], rr[7]};
        }
    }
}

// ---------------- phase kernels ----------------

// transpose weights to bf16 Wt[n][k] AND zero deg (extra blocks)
__global__ void k_prep(const float* __restrict__ W0, const float* __restrict__ S0,
                       const float* __restrict__ W1, const float* __restrict__ S1,
                       const float* __restrict__ W2, const float* __restrict__ S2,
                       unsigned short* __restrict__ wt, int* __restrict__ deg) {
    int idx = blockIdx.x * blockDim.x + threadIdx.x;
    if (idx < WT_TOTAL) {
        const float* W; int OD; int base;
        int r = idx >> 14;
        if (idx < 81920) {
            OD = 128; base = r << 14;
            W = (r == 0) ? W0 : (r == 1) ? S0 : (r == 2) ? W1 : (r == 3) ? S1 : W2;
        } else { W = S2; OD = 32; base = 81920; }
        int off = idx - base;
        int n = off >> 7, k = off & 127;
        wt[idx] = f2bf(W[(size_t)k * OD + n]);
    } else {
        int i = idx - WT_TOTAL;
        if (i < NN) deg[i] = 0;
    }
}

// layer-0 dual GEMM (col-split, 4 variants/row-block) + histogram, one dispatch
__global__ __launch_bounds__(256) void k_gemm0_hist(
    const float* __restrict__ x,
    const unsigned short* __restrict__ Wta, const float* __restrict__ ba, unsigned short* __restrict__ ya,
    const unsigned short* __restrict__ Wtb, const float* __restrict__ bb, unsigned short* __restrict__ yb,
    const int* __restrict__ dst, int* __restrict__ deg) {
    int b = blockIdx.x;
    if (b < 4 * GLF) {
        int wid = threadIdx.x >> 6, lane = threadIdx.x & 63;
        int gb = b >> 2, yy = b & 3;
        int n0 = (gb * 4 + wid) * 32;
        if (n0 >= NN) return;
        int c0 = (yy & 1) * 64;
        if (yy < 2) gemm_wave<float, 128, 4>(x, Wta, ba, ya, n0, c0, lane);
        else        gemm_wave<float, 128, 4>(x, Wtb, bb, yb, n0, c0, lane);
    } else {
        int e = (b - 4 * GLF) * 256 + threadIdx.x;
        if (e < NE) atomicAdd(&deg[dst[e]], 1);
    }
}

__global__ __launch_bounds__(NTHR) void k_scan1(const int* __restrict__ deg,
                                                int* __restrict__ partial,
                                                int* __restrict__ blocksum) {
    __shared__ int sh[NTHR];
    int b = blockIdx.x, t = threadIdx.x;
    int i = b * NTHR + t;
    int d = (i < NN) ? deg[i] : 0;
    sh[t] = d;
    __syncthreads();
    #pragma unroll
    for (int off = 1; off < NTHR; off <<= 1) {
        int v = (t >= off) ? sh[t - off] : 0;
        __syncthreads();
        sh[t] += v;
        __syncthreads();
    }
    if (i < NN) partial[i] = sh[t];
    if (t == NTHR - 1) blocksum[b] = sh[t];
}

// merged scan2+scan3: each block redundantly scans 196 tile sums in-LDS,
// then applies its tile's exclusive offset -> rowptr, cursor.
__global__ __launch_bounds__(NTHR) void k_scan23(const int* __restrict__ deg,
                                                 const int* __restrict__ partial,
                                                 const int* __restrict__ blocksum,
                                                 int* __restrict__ rowptr,
                                                 int* __restrict__ cursor) {
    __shared__ int sh[NTHR];
    int b = blockIdx.x, t = threadIdx.x;
    int v = (t < NTILE) ? blocksum[t] : 0;
    sh[t] = v;
    __syncthreads();
    #pragma unroll
    for (int off = 1; off < NTHR; off <<= 1) {
        int u = (t >= off) ? sh[t - off] : 0;
        __syncthreads();
        sh[t] += u;
        __syncthreads();
    }
    int tile_off = (b > 0) ? sh[b - 1] : 0;
    int i = b * NTHR + t;
    if (i < NN) {
        int inc = partial[i] + tile_off;
        rowptr[i + 1] = inc;
        cursor[i] = inc - deg[i];
        if (i == 0) rowptr[0] = 0;
    }
}

__global__ void k_scatter(const int* __restrict__ src, const int* __restrict__ dst,
                          int* __restrict__ cursor, int* __restrict__ csr_src) {
    int e = blockIdx.x * blockDim.x + threadIdx.x;
    if (e >= NE) return;
    int d = dst[e];
    int pos = atomicAdd(&cursor[d], 1);
    csr_src[pos] = src[e];
}

// l<2 dual GEMM: blockIdx.y in 0..3 -> (h col 0/64, skip col 0/64)
template<typename AT>
__global__ __launch_bounds__(256) void k_gemm_dual_lf(
    const AT* __restrict__ x,
    const unsigned short* __restrict__ Wta, const float* __restrict__ ba, unsigned short* __restrict__ ya,
    const unsigned short* __restrict__ Wtb, const float* __restrict__ bb, unsigned short* __restrict__ yb) {
    int wid = threadIdx.x >> 6, lane = threadIdx.x & 63;
    int n0 = (blockIdx.x * 4 + wid) * 32;
    if (n0 >= NN) return;
    int yy = blockIdx.y;
    int c0 = (yy & 1) * 64;
    if (yy < 2) gemm_wave<AT, 128, 4>(x, Wta, ba, ya, n0, c0, lane);
    else        gemm_wave<AT, 128, 4>(x, Wtb, bb, yb, n0, c0, lane);
}

// l2: blockIdx.y 0/1 -> h col halves, 2 -> skip (OD=32, full width)
__global__ __launch_bounds__(256) void k_gemm_dual_l2(
    const unsigned short* __restrict__ x,
    const unsigned short* __restrict__ Wta, const float* __restrict__ ba, unsigned short* __restrict__ ya,
    const unsigned short* __restrict__ Wtb, const float* __restrict__ bb, unsigned short* __restrict__ yb) {
    int wid = threadIdx.x >> 6, lane = threadIdx.x & 63;
    int n0 = (blockIdx.x * 4 + wid) * 32;
    if (n0 >= NN) return;
    int yy = blockIdx.y;
    if (yy < 2) gemm_wave<unsigned short, 128, 4>(x, Wta, ba, ya, n0, yy * 64, lane);
    else        gemm_wave<unsigned short, 32, 2>(x, Wtb, bb, yb, n0, 0, lane);
}

__global__ __launch_bounds__(256) void k_gat(
    const unsigned short* __restrict__ h, const int* __restrict__ rowptr,
    const int* __restrict__ csr_src, const float* __restrict__ att,
    const float* __restrict__ bias, const unsigned short* __restrict__ skip,
    void* __restrict__ out, int last) {
    int wid = threadIdx.x >> 6;
    int n = blockIdx.x * 4 + wid;
    if (n >= NN) return;
    gat_node(n, threadIdx.x & 63, h, rowptr, csr_src, att, bias, skip, out, last);
}

extern "C" void kernel_launch(void* const* d_in, const int* in_sizes, int n_in,
                              void* d_out, int out_size, void* d_ws, size_t ws_size,
                              hipStream_t stream) {
    const float* x0 = (const float*)d_in[0];
    const int* ei = (const int*)d_in[1];
    const int* src = ei;
    const int* dst = ei + NE;

    unsigned short* xbuf = (unsigned short*)d_ws;            // NN*HC bf16
    unsigned short* h    = xbuf + (size_t)NN * HC;           // NN*HC bf16
    unsigned short* skip = h + (size_t)NN * HC;              // NN*HC bf16
    int* deg     = (int*)(skip + (size_t)NN * HC);           // NN
    int* rowptr  = deg + NN;                                 // NN+1
    int* cursor  = rowptr + NN + 1;                          // NN
    int* partial = cursor + NN;                              // NN
    int* blocksum = partial + NN;                            // NTILE
    uintptr_t pa = (uintptr_t)(blocksum + NTILE);
    pa = (pa + 15) & ~(uintptr_t)15;
    unsigned short* wt = (unsigned short*)pa;                // WT_TOTAL bf16
    int* csr_src = (int*)(wt + WT_TOTAL);                    // NE

    unsigned short* wtW[3] = {wt, wt + 32768, wt + 65536};
    unsigned short* wtS[3] = {wt + 16384, wt + 49152, wt + 81920};

    const float* linb0  = (const float*)d_in[3];
    const float* skipb0 = (const float*)d_in[7];

    // 1) prep: transpose weights, zero deg
    k_prep<<<(WT_TOTAL + NN + 255) / 256, 256, 0, stream>>>(
        (const float*)d_in[2], (const float*)d_in[6],
        (const float*)d_in[8], (const float*)d_in[12],
        (const float*)d_in[14], (const float*)d_in[18], wt, deg);

    // 2) layer-0 dual GEMM (col-split) + histogram (one dispatch)
    k_gemm0_hist<<<4 * GLF + GHIST, 256, 0, stream>>>(
        x0, wtW[0], linb0, h, wtS[0], skipb0, skip, dst, deg);

    // 3-5) CSR: scan, apply, scatter (full-width kernels)
    k_scan1<<<NTILE, NTHR, 0, stream>>>(deg, partial, blocksum);
    k_scan23<<<NTILE, NTHR, 0, stream>>>(deg, partial, blocksum, rowptr, cursor);
    k_scatter<<<GHIST, 256, 0, stream>>>(src, dst, cursor, csr_src);

    const int GGAT = (NN + 3) / 4;

    for (int l = 0; l < 3; ++l) {
        const float* linb  = (const float*)d_in[2 + 6 * l + 1];
        const float* att   = (const float*)d_in[2 + 6 * l + 2];
        const float* bias  = (const float*)d_in[2 + 6 * l + 3];
        const float* skipb = (const float*)d_in[2 + 6 * l + 5];

        if (l == 1) {
            k_gemm_dual_lf<unsigned short><<<dim3(GLF, 4), 256, 0, stream>>>(
                xbuf, wtW[1], linb, h, wtS[1], skipb, skip);
        } else if (l == 2) {
            k_gemm_dual_l2<<<dim3(GLF, 3), 256, 0, stream>>>(
                xbuf, wtW[2], linb, h, wtS[2], skipb, skip);
        }
        void* outp = (l < 2) ? (void*)xbuf : (void*)d_out;
        k_gat<<<GGAT, 256, 0, stream>>>(h, rowptr, csr_src, att, bias, skip, outp, l == 2);
    }
}

// Round 20
// 329.625 us; speedup vs baseline: 1.1701x; 1.0527x over previous
//
#include <hip/hip_runtime.h>
#include <hip/hip_bf16.h>

#define NN 50000
#define NE 600000
#define IN_DIM 128
#define HC 128      // H*C
#define NH 4
#define NC 32
#define NEG_SLOPE 0.2f

#define NTHR 256
#define NTILE 196           // ceil(NN/256) scan tiles
#define WT_TOTAL 86016
#define GLF 391             // ceil(NN/128): 4 waves x 32 rows per block
#define GHIST 2344          // ceil(NE/256)

typedef __attribute__((ext_vector_type(8))) short short8;
typedef __attribute__((ext_vector_type(4))) float floatx4;
typedef __attribute__((ext_vector_type(8))) unsigned short ushort8v;

__device__ __forceinline__ float bf2f(unsigned short u) {
    return __uint_as_float(((unsigned)u) << 16);
}
__device__ __forceinline__ unsigned short f2bf(float f) {
    unsigned u = __float_as_uint(f);
    unsigned r = (u + 0x7FFFu + ((u >> 16) & 1u)) >> 16;   // RNE
    return (unsigned short)r;
}

// ============ LDS-free MFMA GEMM wave: 32 rows x (NTC*16) cols, K=128 ============
// Wt stored in fragment order [ks][colgroup][quad][l16][8] -> every Wt wave-load
// is 64 lanes x 16 B CONTIGUOUS (1 KB, 4 cache lines instead of 16).
// mfma(A=Wt frag, B=x frag) -> D[m=channel][n=node]; packed bf16 stores.
template<typename AT, int OD, int NTC>
__device__ __forceinline__ void gemm_wave(
    const AT* __restrict__ x, const unsigned short* __restrict__ Wt,
    const float* __restrict__ b, unsigned short* __restrict__ y,
    int n0, int c016, int lane) {
    int quad = lane >> 4, l16 = lane & 15;
    floatx4 acc[2][NTC];
    #pragma unroll
    for (int i = 0; i < 2; ++i)
        #pragma unroll
        for (int j = 0; j < NTC; ++j) acc[i][j] = (floatx4){0.f, 0.f, 0.f, 0.f};

    int r0 = n0 + l16;      if (r0 >= NN) r0 = NN - 1;
    int r1 = n0 + 16 + l16; if (r1 >= NN) r1 = NN - 1;
    int lidx = (quad * 16 + l16) * 8;   // lane's slot within a 1 KB fragment group

    #pragma unroll
    for (int ks = 0; ks < 4; ++ks) {
        int kb = ks * 32 + quad * 8;
        short8 xb0, xb1;
        if constexpr (sizeof(AT) == 4) {
            const float* xr = (const float*)x;
            float4 v0 = *(const float4*)&xr[(size_t)r0 * IN_DIM + kb];
            float4 v1 = *(const float4*)&xr[(size_t)r0 * IN_DIM + kb + 4];
            float4 u0 = *(const float4*)&xr[(size_t)r1 * IN_DIM + kb];
            float4 u1 = *(const float4*)&xr[(size_t)r1 * IN_DIM + kb + 4];
            xb0 = (short8){(short)f2bf(v0.x), (short)f2bf(v0.y), (short)f2bf(v0.z), (short)f2bf(v0.w),
                           (short)f2bf(v1.x), (short)f2bf(v1.y), (short)f2bf(v1.z), (short)f2bf(v1.w)};
            xb1 = (short8){(short)f2bf(u0.x), (short)f2bf(u0.y), (short)f2bf(u0.z), (short)f2bf(u0.w),
                           (short)f2bf(u1.x), (short)f2bf(u1.y), (short)f2bf(u1.z), (short)f2bf(u1.w)};
        } else {
            xb0 = *(const short8*)&((const unsigned short*)x)[(size_t)r0 * IN_DIM + kb];
            xb1 = *(const short8*)&((const unsigned short*)x)[(size_t)r1 * IN_DIM + kb];
        }
        #pragma unroll
        for (int tc = 0; tc < NTC; ++tc) {
            int grp = ks * (OD / 16) + c016 + tc;       // fragment group index
            short8 af = *(const short8*)&Wt[grp * 512 + lidx];
            acc[0][tc] = __builtin_amdgcn_mfma_f32_16x16x32_bf16(af, xb0, acc[0][tc], 0, 0, 0);
            acc[1][tc] = __builtin_amdgcn_mfma_f32_16x16x32_bf16(af, xb1, acc[1][tc], 0, 0, 0);
        }
    }

    #pragma unroll
    for (int tc = 0; tc < NTC; ++tc) {
        int cbase = (c016 + tc) * 16 + quad * 4;
        float4 bv = *(const float4*)&b[cbase];
        #pragma unroll
        for (int i = 0; i < 2; ++i) {
            int node = n0 + i * 16 + l16;
            if (node < NN) {
                ushort4 pk = {f2bf(acc[i][tc][0] + bv.x), f2bf(acc[i][tc][1] + bv.y),
                              f2bf(acc[i][tc][2] + bv.z), f2bf(acc[i][tc][3] + bv.w)};
                *(ushort4*)&y[(size_t)node * OD + cbase] = pk;
            }
        }
    }
}

// ---------------- per-node GATv2 (1 wave, 4 slots x 16 lanes) ----------------
// Score via leaky(v) = 0.6v + 0.4|v|. csr entries are premultiplied by HC.
__device__ __forceinline__ void gat_node(
    int n, int lane, const unsigned short* __restrict__ h, const int* __restrict__ rowptr,
    const int* __restrict__ csr_src, const float* __restrict__ att,
    const float* __restrict__ bias, const unsigned short* __restrict__ skip,
    void* __restrict__ out, int last) {
    int slot = lane >> 4;
    int t = lane & 15;

    ushort8v hdv = *(const ushort8v*)(h + (size_t)n * HC + t * 8);
    float hd[8], av[8];
    #pragma unroll
    for (int c = 0; c < 8; ++c) hd[c] = bf2f(hdv[c]);
    float4 av0 = ((const float4*)att)[t * 2];
    float4 av1 = ((const float4*)att)[t * 2 + 1];
    av[0] = av0.x; av[1] = av0.y; av[2] = av0.z; av[3] = av0.w;
    av[4] = av1.x; av[5] = av1.y; av[6] = av1.z; av[7] = av1.w;

    float K = 0.f;
    #pragma unroll
    for (int c = 0; c < 8; ++c) K = fmaf(hd[c], av[c], K);

    int beg = rowptr[n], end = rowptr[n + 1];
    float l = 0.f;
    float acc[8] = {};

    int i0 = beg + slot;
    const unsigned short* hp = h + t * 8;
    ushort8v b0 = 0, b1 = 0;
    if (i0 < end)     b0 = *(const ushort8v*)(hp + csr_src[i0]);
    if (i0 + 4 < end) b1 = *(const ushort8v*)(hp + csr_src[i0 + 4]);

    for (int i = i0; i < end; i += 4) {
        float hs[8];
        float S1 = K, S2 = 0.f;
        #pragma unroll
        for (int c = 0; c < 8; ++c) {
            float hsv = bf2f(b0[c]);
            hs[c] = hsv;
            S1 = fmaf(hsv, av[c], S1);
            S2 = fmaf(fabsf(hsv + hd[c]), av[c], S2);
        }
        b0 = b1;
        if (i + 8 < end)
            b1 = *(const ushort8v*)(hp + csr_src[i + 8]);
        float part = fmaf(0.6f, S1, 0.4f * S2);
        part += __shfl_xor(part, 1, 64);
        part += __shfl_xor(part, 2, 64);
        float p = __expf(part);
        #pragma unroll
        for (int c = 0; c < 8; ++c) acc[c] = fmaf(p, hs[c], acc[c]);
        l += p;
    }

    l += __shfl_xor(l, 16, 64);
    l += __shfl_xor(l, 32, 64);
    #pragma unroll
    for (int c = 0; c < 8; ++c) {
        acc[c] += __shfl_xor(acc[c], 16, 64);
        acc[c] += __shfl_xor(acc[c], 32, 64);
    }

    float inv = 1.f / fmaxf(l, 1e-16f);
    float o[8];
    #pragma unroll
    for (int c = 0; c < 8; ++c) o[c] = acc[c] * inv;

    if (!last) {
        if (lane < 16) {
            float4 bv0 = ((const float4*)bias)[t * 2];
            float4 bv1 = ((const float4*)bias)[t * 2 + 1];
            float bb[8] = {bv0.x, bv0.y, bv0.z, bv0.w, bv1.x, bv1.y, bv1.z, bv1.w};
            ushort8v skv = *(const ushort8v*)(skip + (size_t)n * HC + t * 8);
            ushort8v ov;
            #pragma unroll
            for (int c = 0; c < 8; ++c) {
                float r = o[c] + bb[c] + bf2f(skv[c]);
                r = r > 0.f ? r : (__expf(r) - 1.f);   // ELU
                ov[c] = f2bf(r);
            }
            *(ushort8v*)((unsigned short*)out + (size_t)n * HC + t * 8) = ov;
        }
    } else {
        float r4[8], r8[8], r12[8];
        #pragma unroll
        for (int c = 0; c < 8; ++c) {
            r4[c]  = __shfl_down(o[c], 4, 64);
            r8[c]  = __shfl_down(o[c], 8, 64);
            r12[c] = __shfl_down(o[c], 12, 64);
        }
        if (lane < 4) {
            float* op = (float*)out + (size_t)n * NC + lane * 8;
            ushort8v skv = *(const ushort8v*)(skip + (size_t)n * NC + lane * 8);
            float rr[8];
            #pragma unroll
            for (int c = 0; c < 8; ++c) {
                rr[c] = 0.25f * (o[c] + r4[c] + r8[c] + r12[c])
                      + bias[lane * 8 + c] + bf2f(skv[c]);
            }
            *(float4*)op = (float4){rr[0], rr[1], rr[2], rr[3]};
            *(float4*)(op + 4) = (float4){rr[4], rr[5], rr[6], rr[7]};
        }
    }
}

// ---------------- phase kernels ----------------

// transpose weights to bf16 fragment-ordered Wt AND zero deg (extra blocks).
// Layout per matrix: short idx = ((ks*(OD/16)+cg)*4 + quad)*128 + l16*8 + j,
// holding W[k][col] with k = ks*32+quad*8+j, col = cg*16+l16.
__global__ void k_prep(const float* __restrict__ W0, const float* __restrict__ S0,
                       const float* __restrict__ W1, const float* __restrict__ S1,
                       const float* __restrict__ W2, const float* __restrict__ S2,
                       unsigned short* __restrict__ wt, int* __restrict__ deg) {
    int idx = blockIdx.x * blockDim.x + threadIdx.x;
    if (idx < WT_TOTAL) {
        if (idx < 81920) {          // five OD=128 matrices, 16384 shorts each
            int r = idx >> 14;
            const float* W = (r == 0) ? W0 : (r == 1) ? S0 : (r == 2) ? W1 : (r == 3) ? S1 : W2;
            int off = idx & 16383;
            int j = off & 7, l16 = (off >> 3) & 15, quad = (off >> 7) & 3;
            int cg = (off >> 9) & 7, ks = off >> 12;
            int k = ks * 32 + quad * 8 + j;
            int col = cg * 16 + l16;
            wt[idx] = f2bf(W[(size_t)k * 128 + col]);
        } else {                    // S2: OD=32, 4096 shorts
            int off = idx - 81920;
            int j = off & 7, l16 = (off >> 3) & 15, quad = (off >> 7) & 3;
            int cg = (off >> 9) & 1, ks = off >> 10;
            int k = ks * 32 + quad * 8 + j;
            int col = cg * 16 + l16;
            wt[idx] = f2bf(S2[(size_t)k * 32 + col]);
        }
    } else {
        int i = idx - WT_TOTAL;
        if (i < NN) deg[i] = 0;
    }
}

// layer-0 dual GEMM (col-split) + histogram, one dispatch
__global__ __launch_bounds__(256) void k_gemm0_hist(
    const float* __restrict__ x,
    const unsigned short* __restrict__ Wta, const float* __restrict__ ba, unsigned short* __restrict__ ya,
    const unsigned short* __restrict__ Wtb, const float* __restrict__ bb, unsigned short* __restrict__ yb,
    const int* __restrict__ dst, int* __restrict__ deg) {
    int b = blockIdx.x;
    if (b < 4 * GLF) {
        int wid = threadIdx.x >> 6, lane = threadIdx.x & 63;
        int gb = b >> 2, yy = b & 3;
        int n0 = (gb * 4 + wid) * 32;
        if (n0 >= NN) return;
        int c016 = (yy & 1) * 4;
        if (yy < 2) gemm_wave<float, 128, 4>(x, Wta, ba, ya, n0, c016, lane);
        else        gemm_wave<float, 128, 4>(x, Wtb, bb, yb, n0, c016, lane);
    } else {
        int e = (b - 4 * GLF) * 256 + threadIdx.x;
        if (e < NE) atomicAdd(&deg[dst[e]], 1);
    }
}

__global__ __launch_bounds__(NTHR) void k_scan1(const int* __restrict__ deg,
                                                int* __restrict__ partial,
                                                int* __restrict__ blocksum) {
    __shared__ int sh[NTHR];
    int b = blockIdx.x, t = threadIdx.x;
    int i = b * NTHR + t;
    int d = (i < NN) ? deg[i] : 0;
    sh[t] = d;
    __syncthreads();
    #pragma unroll
    for (int off = 1; off < NTHR; off <<= 1) {
        int v = (t >= off) ? sh[t - off] : 0;
        __syncthreads();
        sh[t] += v;
        __syncthreads();
    }
    if (i < NN) partial[i] = sh[t];
    if (t == NTHR - 1) blocksum[b] = sh[t];
}

__global__ __launch_bounds__(NTHR) void k_scan23(const int* __restrict__ deg,
                                                 const int* __restrict__ partial,
                                                 const int* __restrict__ blocksum,
                                                 int* __restrict__ rowptr,
                                                 int* __restrict__ cursor) {
    __shared__ int sh[NTHR];
    int b = blockIdx.x, t = threadIdx.x;
    int v = (t < NTILE) ? blocksum[t] : 0;
    sh[t] = v;
    __syncthreads();
    #pragma unroll
    for (int off = 1; off < NTHR; off <<= 1) {
        int u = (t >= off) ? sh[t - off] : 0;
        __syncthreads();
        sh[t] += u;
        __syncthreads();
    }
    int tile_off = (b > 0) ? sh[b - 1] : 0;
    int i = b * NTHR + t;
    if (i < NN) {
        int inc = partial[i] + tile_off;
        rowptr[i + 1] = inc;
        cursor[i] = inc - deg[i];
        if (i == 0) rowptr[0] = 0;
    }
}

// csr entries premultiplied by HC (element offset into h)
__global__ void k_scatter(const int* __restrict__ src, const int* __restrict__ dst,
                          int* __restrict__ cursor, int* __restrict__ csr_src) {
    int e = blockIdx.x * blockDim.x + threadIdx.x;
    if (e >= NE) return;
    int d = dst[e];
    int pos = atomicAdd(&cursor[d], 1);
    csr_src[pos] = src[e] * HC;
}

// l<2 dual GEMM: blockIdx.y in 0..3 -> (h col-half 0/1, skip col-half 0/1)
template<typename AT>
__global__ __launch_bounds__(256) void k_gemm_dual_lf(
    const AT* __restrict__ x,
    const unsigned short* __restrict__ Wta, const float* __restrict__ ba, unsigned short* __restrict__ ya,
    const unsigned short* __restrict__ Wtb, const float* __restrict__ bb, unsigned short* __restrict__ yb) {
    int wid = threadIdx.x >> 6, lane = threadIdx.x & 63;
    int n0 = (blockIdx.x * 4 + wid) * 32;
    if (n0 >= NN) return;
    int yy = blockIdx.y;
    int c016 = (yy & 1) * 4;
    if (yy < 2) gemm_wave<AT, 128, 4>(x, Wta, ba, ya, n0, c016, lane);
    else        gemm_wave<AT, 128, 4>(x, Wtb, bb, yb, n0, c016, lane);
}

// l2: blockIdx.y 0/1 -> h col halves, 2 -> skip (OD=32, full width)
__global__ __launch_bounds__(256) void k_gemm_dual_l2(
    const unsigned short* __restrict__ x,
    const unsigned short* __restrict__ Wta, const float* __restrict__ ba, unsigned short* __restrict__ ya,
    const unsigned short* __restrict__ Wtb, const float* __restrict__ bb, unsigned short* __restrict__ yb) {
    int wid = threadIdx.x >> 6, lane = threadIdx.x & 63;
    int n0 = (blockIdx.x * 4 + wid) * 32;
    if (n0 >= NN) return;
    int yy = blockIdx.y;
    if (yy < 2) gemm_wave<unsigned short, 128, 4>(x, Wta, ba, ya, n0, yy * 4, lane);
    else        gemm_wave<unsigned short, 32, 2>(x, Wtb, bb, yb, n0, 0, lane);
}

__global__ __launch_bounds__(256) void k_gat(
    const unsigned short* __restrict__ h, const int* __restrict__ rowptr,
    const int* __restrict__ csr_src, const float* __restrict__ att,
    const float* __restrict__ bias, const unsigned short* __restrict__ skip,
    void* __restrict__ out, int last) {
    int wid = threadIdx.x >> 6;
    int n = blockIdx.x * 4 + wid;
    if (n >= NN) return;
    gat_node(n, threadIdx.x & 63, h, rowptr, csr_src, att, bias, skip, out, last);
}

extern "C" void kernel_launch(void* const* d_in, const int* in_sizes, int n_in,
                              void* d_out, int out_size, void* d_ws, size_t ws_size,
                              hipStream_t stream) {
    const float* x0 = (const float*)d_in[0];
    const int* ei = (const int*)d_in[1];
    const int* src = ei;
    const int* dst = ei + NE;

    unsigned short* xbuf = (unsigned short*)d_ws;            // NN*HC bf16
    unsigned short* h    = xbuf + (size_t)NN * HC;           // NN*HC bf16
    unsigned short* skip = h + (size_t)NN * HC;              // NN*HC bf16
    int* deg     = (int*)(skip + (size_t)NN * HC);           // NN
    int* rowptr  = deg + NN;                                 // NN+1
    int* cursor  = rowptr + NN + 1;                          // NN
    int* partial = cursor + NN;                              // NN
    int* blocksum = partial + NN;                            // NTILE
    uintptr_t pa = (uintptr_t)(blocksum + NTILE);
    pa = (pa + 15) & ~(uintptr_t)15;
    unsigned short* wt = (unsigned short*)pa;                // WT_TOTAL bf16
    int* csr_src = (int*)(wt + WT_TOTAL);                    // NE

    unsigned short* wtW[3] = {wt, wt + 32768, wt + 65536};
    unsigned short* wtS[3] = {wt + 16384, wt + 49152, wt + 81920};

    const float* linb0  = (const float*)d_in[3];
    const float* skipb0 = (const float*)d_in[7];

    // 1) prep: fragment-order transpose of weights, zero deg
    k_prep<<<(WT_TOTAL + NN + 255) / 256, 256, 0, stream>>>(
        (const float*)d_in[2], (const float*)d_in[6],
        (const float*)d_in[8], (const float*)d_in[12],
        (const float*)d_in[14], (const float*)d_in[18], wt, deg);

    // 2) layer-0 dual GEMM (col-split) + histogram (one dispatch)
    k_gemm0_hist<<<4 * GLF + GHIST, 256, 0, stream>>>(
        x0, wtW[0], linb0, h, wtS[0], skipb0, skip, dst, deg);

    // 3-5) CSR: scan, apply, scatter (full-width kernels)
    k_scan1<<<NTILE, NTHR, 0, stream>>>(deg, partial, blocksum);
    k_scan23<<<NTILE, NTHR, 0, stream>>>(deg, partial, blocksum, rowptr, cursor);
    k_scatter<<<GHIST, 256, 0, stream>>>(src, dst, cursor, csr_src);

    const int GGAT = (NN + 3) / 4;

    for (int l = 0; l < 3; ++l) {
        const float* linb  = (const float*)d_in[2 + 6 * l + 1];
        const float* att   = (const float*)d_in[2 + 6 * l + 2];
        const float* bias  = (const float*)d_in[2 + 6 * l + 3];
        const float* skipb = (const float*)d_in[2 + 6 * l + 5];

        if (l == 1) {
            k_gemm_dual_lf<unsigned short><<<dim3(GLF, 4), 256, 0, stream>>>(
                xbuf, wtW[1], linb, h, wtS[1], skipb, skip);
        } else if (l == 2) {
            k_gemm_dual_l2<<<dim3(GLF, 3), 256, 0, stream>>>(
                xbuf, wtW[2], linb, h, wtS[2], skipb, skip);
        }
        void* outp = (l < 2) ? (void*)xbuf : (void*)d_out;
        k_gat<<<GGAT, 256, 0, stream>>>(h, rowptr, csr_src, att, bias, skip, outp, l == 2);
    }
}